// Round 1
// baseline (1122.829 us; speedup 1.0000x reference)
//
#include <hip/hip_runtime.h>
#include <hip/hip_bf16.h>
#include <math.h>

// Problem constants
#define Mrows 4096      // B*T
#define Kdim  256       // F
#define Ncols 16384     // G*V
#define Vsz   8192
#define DGsz  8

// ---------------- GEMM: hidden[n][j] = x[n,:].W[j,:] + b[j] (fp32) -------------
#define BM 128
#define BN 128
#define BK 16

__global__ __launch_bounds__(256) void gemm_fp32(const float* __restrict__ x,
                                                 const float* __restrict__ w,
                                                 const float* __restrict__ bias,
                                                 float* __restrict__ hid,
                                                 int r0) {
    __shared__ float As[BK][BM + 4];
    __shared__ float Bs[BK][BN + 4];
    const int tid = threadIdx.x;
    const int bm = blockIdx.y * BM;          // row offset within chunk
    const int bn = blockIdx.x * BN;          // column offset (j)
    const int mr = (tid / 16) * 8;
    const int nr = (tid % 16) * 8;

    float acc[8][8];
#pragma unroll
    for (int i = 0; i < 8; ++i)
#pragma unroll
        for (int j = 0; j < 8; ++j) acc[i][j] = 0.f;

    for (int k0 = 0; k0 < Kdim; k0 += BK) {
#pragma unroll
        for (int p = tid; p < 512; p += 256) {
            const int m = p >> 2;
            const int kq = (p & 3) * 4;
            const float4 av = *(const float4*)(x + (size_t)(r0 + bm + m) * Kdim + k0 + kq);
            As[kq + 0][m] = av.x; As[kq + 1][m] = av.y;
            As[kq + 2][m] = av.z; As[kq + 3][m] = av.w;
            const float4 bv = *(const float4*)(w + (size_t)(bn + m) * Kdim + k0 + kq);
            Bs[kq + 0][m] = bv.x; Bs[kq + 1][m] = bv.y;
            Bs[kq + 2][m] = bv.z; Bs[kq + 3][m] = bv.w;
        }
        __syncthreads();
#pragma unroll
        for (int k = 0; k < BK; ++k) {
            float4 a0 = *(const float4*)&As[k][mr];
            float4 a1 = *(const float4*)&As[k][mr + 4];
            float4 b0 = *(const float4*)&Bs[k][nr];
            float4 b1 = *(const float4*)&Bs[k][nr + 4];
            float a[8] = {a0.x, a0.y, a0.z, a0.w, a1.x, a1.y, a1.z, a1.w};
            float b[8] = {b0.x, b0.y, b0.z, b0.w, b1.x, b1.y, b1.z, b1.w};
#pragma unroll
            for (int i = 0; i < 8; ++i)
#pragma unroll
                for (int j = 0; j < 8; ++j) acc[i][j] = fmaf(a[i], b[j], acc[i][j]);
        }
        __syncthreads();
    }

    float bb[8];
#pragma unroll
    for (int j = 0; j < 8; ++j) bb[j] = bias[bn + nr + j];
#pragma unroll
    for (int i = 0; i < 8; ++i) {
        float4 o0 = {acc[i][0] + bb[0], acc[i][1] + bb[1], acc[i][2] + bb[2], acc[i][3] + bb[3]};
        float4 o1 = {acc[i][4] + bb[4], acc[i][5] + bb[5], acc[i][6] + bb[6], acc[i][7] + bb[7]};
        float* dst = hid + (size_t)(bm + mr + i) * Ncols + bn + nr;
        *(float4*)dst = o0;
        *(float4*)(dst + 4) = o1;
    }
}

// ---------------- Phase 2: softmax x2, argmax, codevectors, marginal -----------
#define ROWSPB 8   // rows (n) per block, fixed g

__global__ __launch_bounds__(256) void phase2(const float* __restrict__ hid,
                                              const float* __restrict__ u,
                                              const float* __restrict__ emb,
                                              const int* __restrict__ mask,
                                              float* __restrict__ marginal,
                                              float* __restrict__ out,
                                              int r0) {
    const int g = blockIdx.y;
    const int n0 = r0 + blockIdx.x * ROWSPB;
    const int tid = threadIdx.x;
    const int lane = tid & 63;
    const int wid = tid >> 6;

    __shared__ float sv1[4]; __shared__ int si1[4]; __shared__ float sv2[4];
    __shared__ float ss1[4]; __shared__ float ss2[4];
    __shared__ float scv[4][8];

    float marg[32];
#pragma unroll
    for (int i = 0; i < 32; ++i) marg[i] = 0.f;

    for (int r = 0; r < ROWSPB; ++r) {
        const int n = n0 + r;
        const float* hrow = hid + (size_t)(n - r0) * Ncols + (size_t)g * Vsz;
        const float* urow = u + ((size_t)n * 2 + g) * Vsz;

        float h[32], lg[32];
        float mx1 = -INFINITY, mx2 = -INFINITY;
        int amax = 0;
#pragma unroll
        for (int i = 0; i < 32; ++i) {
            const int v = tid + (i << 8);
            const float hv = hrow[v];
            float uu = urow[v];
            uu = fminf(fmaxf(uu, 1.17549435e-38f), 1.0f);
            // gumbel = -log(-log(u)); accurate logf (v_log_f32 abs-error blows up near u->1)
            const float l1 = logf(uu);
            const float gum = -logf(-l1);
            const float l = hv + gum;   // temperature = 1
            h[i] = hv; lg[i] = l;
            if (l > mx1) { mx1 = l; amax = v; }
            mx2 = fmaxf(mx2, hv);
        }
        // block reduce (max1+idx, max2)
        float v1 = mx1; int i1 = amax; float v2 = mx2;
#pragma unroll
        for (int off = 32; off > 0; off >>= 1) {
            float ov = __shfl_down(v1, off, 64);
            int oi = __shfl_down(i1, off, 64);
            if (ov > v1 || (ov == v1 && oi < i1)) { v1 = ov; i1 = oi; }
            v2 = fmaxf(v2, __shfl_down(v2, off, 64));
        }
        __syncthreads();
        if (lane == 0) { sv1[wid] = v1; si1[wid] = i1; sv2[wid] = v2; }
        __syncthreads();
        if (tid == 0) {
            float bv = sv1[0]; int bi = si1[0]; float b2 = sv2[0];
            for (int wv = 1; wv < 4; ++wv) {
                if (sv1[wv] > bv || (sv1[wv] == bv && si1[wv] < bi)) { bv = sv1[wv]; bi = si1[wv]; }
                b2 = fmaxf(b2, sv2[wv]);
            }
            sv1[0] = bv; si1[0] = bi; sv2[0] = b2;
        }
        __syncthreads();
        const float M1 = sv1[0];
        const float M2 = sv2[0];
        const int AMAX = si1[0];

        // pass B: sums + codevector accumulation; h[] becomes clean exp terms
        float s1 = 0.f, s2 = 0.f;
        float cv[8];
#pragma unroll
        for (int d = 0; d < 8; ++d) cv[d] = 0.f;
#pragma unroll
        for (int i = 0; i < 32; ++i) {
            const int v = tid + (i << 8);
            const float p = __expf(lg[i] - M1);
            s1 += p;
            const float4 e0 = *(const float4*)(emb + ((size_t)(g * Vsz + v)) * DGsz);
            const float4 e1 = *(const float4*)(emb + ((size_t)(g * Vsz + v)) * DGsz + 4);
            cv[0] = fmaf(p, e0.x, cv[0]); cv[1] = fmaf(p, e0.y, cv[1]);
            cv[2] = fmaf(p, e0.z, cv[2]); cv[3] = fmaf(p, e0.w, cv[3]);
            cv[4] = fmaf(p, e1.x, cv[4]); cv[5] = fmaf(p, e1.y, cv[5]);
            cv[6] = fmaf(p, e1.z, cv[6]); cv[7] = fmaf(p, e1.w, cv[7]);
            const float q = __expf(h[i] - M2);
            s2 += q;
            h[i] = q;
        }
#pragma unroll
        for (int off = 32; off > 0; off >>= 1) {
            s1 += __shfl_down(s1, off, 64);
            s2 += __shfl_down(s2, off, 64);
        }
#pragma unroll
        for (int d = 0; d < 8; ++d)
#pragma unroll
            for (int off = 32; off > 0; off >>= 1) cv[d] += __shfl_down(cv[d], off, 64);
        if (lane == 0) {
            ss1[wid] = s1; ss2[wid] = s2;
#pragma unroll
            for (int d = 0; d < 8; ++d) scv[wid][d] = cv[d];
        }
        __syncthreads();
        const float S1 = ss1[0] + ss1[1] + ss1[2] + ss1[3];
        const float S2 = ss2[0] + ss2[1] + ss2[2] + ss2[3];
        if (tid < 8) {
            const float c = scv[0][tid] + scv[1][tid] + scv[2][tid] + scv[3][tid];
            out[(size_t)n * 16 + g * 8 + tid] = c / S1;
        }
        if (tid == 8) out[65537 + (size_t)n * 2 + g] = (float)AMAX;

        if (mask[n] != 0) {
            const float invS2 = 1.0f / S2;
#pragma unroll
            for (int i = 0; i < 32; ++i) marg[i] = fmaf(h[i], invS2, marg[i]);
        }
        __syncthreads();  // protect shared reuse next row
    }
#pragma unroll
    for (int i = 0; i < 32; ++i)
        atomicAdd(&marginal[g * Vsz + tid + (i << 8)], marg[i]);
}

// ---------------- Perplexity ---------------------------------------------------
__global__ __launch_bounds__(256) void ppl_kernel(const float* __restrict__ marginal,
                                                  const int* __restrict__ mask,
                                                  float* __restrict__ out) {
    const int tid = threadIdx.x;
    const int lane = tid & 63;
    const int wid = tid >> 6;
    __shared__ float red[4];
    __shared__ int redi[4];

    int ms = 0;
    for (int i = tid; i < Mrows; i += 256) ms += mask[i];
#pragma unroll
    for (int off = 32; off > 0; off >>= 1) ms += __shfl_down(ms, off, 64);
    if (lane == 0) redi[wid] = ms;
    __syncthreads();
    const float inv = 1.0f / (float)(redi[0] + redi[1] + redi[2] + redi[3]);

    float ppl = 0.f;
    for (int g = 0; g < 2; ++g) {
        float part = 0.f;
        for (int v = tid; v < Vsz; v += 256) {
            const float m = marginal[g * Vsz + v] * inv;
            part += m * logf(m + 1e-7f);
        }
#pragma unroll
        for (int off = 32; off > 0; off >>= 1) part += __shfl_down(part, off, 64);
        __syncthreads();
        if (lane == 0) red[wid] = part;
        __syncthreads();
        if (tid == 0) ppl += __expf(-(red[0] + red[1] + red[2] + red[3]));
        __syncthreads();
    }
    if (tid == 0) out[65536] = ppl;
}

// ---------------- Launch -------------------------------------------------------
extern "C" void kernel_launch(void* const* d_in, const int* in_sizes, int n_in,
                              void* d_out, int out_size, void* d_ws, size_t ws_size,
                              hipStream_t stream) {
    const float* x    = (const float*)d_in[0];
    const float* u    = (const float*)d_in[1];
    const float* emb  = (const float*)d_in[2];
    const float* w    = (const float*)d_in[3];
    const float* bias = (const float*)d_in[4];
    const int*   mask = (const int*)d_in[5];
    float* out = (float*)d_out;
    float* wsf = (float*)d_ws;

    float* marginal = wsf;            // 16384 floats
    float* hid = wsf + 16384;         // chunk of hidden rows

    // adapt chunk size to available workspace (rows multiple of 128)
    size_t rows_cap = (ws_size / 4 > 16384) ? (ws_size / 4 - 16384) / Ncols : 0;
    int cr = (rows_cap >= Mrows) ? Mrows : (int)((rows_cap / 128) * 128);
    if (cr < 128) cr = 128;

    hipMemsetAsync(marginal, 0, 16384 * sizeof(float), stream);

    for (int r0 = 0; r0 < Mrows; r0 += cr) {
        const int rows = (Mrows - r0 < cr) ? (Mrows - r0) : cr;
        dim3 ggrid(Ncols / BN, rows / BM);
        gemm_fp32<<<ggrid, 256, 0, stream>>>(x, w, bias, hid, r0);
        dim3 pgrid(rows / ROWSPB, 2);
        phase2<<<pgrid, 256, 0, stream>>>(hid, u, emb, mask, marginal, out, r0);
    }
    ppl_kernel<<<1, 256, 0, stream>>>(marginal, mask, out);
}

// Round 2
// 902.048 us; speedup vs baseline: 1.2448x; 1.2448x over previous
//
#include <hip/hip_runtime.h>
#include <hip/hip_bf16.h>
#include <math.h>

#define Mrows 4096      // B*T
#define Kdim  256       // F
#define Ncols 16384     // G*V
#define Vsz   8192

typedef __attribute__((ext_vector_type(8))) short bf16x8;
typedef __attribute__((ext_vector_type(4))) float f32x4;

// ---------------- split fp32 -> bf16 (hi, lo) ---------------------------------
__global__ __launch_bounds__(256) void split_bf16(const float* __restrict__ src,
                                                  __hip_bfloat16* __restrict__ hi,
                                                  __hip_bfloat16* __restrict__ lo) {
    const int i = blockIdx.x * 256 + threadIdx.x;
    const float v = src[i];
    const __hip_bfloat16 h = __float2bfloat16(v);
    const float hf = __bfloat162float(h);
    hi[i] = h;
    lo[i] = __float2bfloat16(v - hf);
}

// ---------------- GEMM: hid[m][n] = sum_k A[m][k]*B[n][k] + bias[n] -----------
// split-bf16 3-term MFMA (ah*bh + ah*bl + al*bh), 128x128 tile, BK=32
__global__ __launch_bounds__(256) void gemm_mfma(const __hip_bfloat16* __restrict__ Ahi,
                                                 const __hip_bfloat16* __restrict__ Alo,
                                                 const __hip_bfloat16* __restrict__ Bhi,
                                                 const __hip_bfloat16* __restrict__ Blo,
                                                 const float* __restrict__ bias,
                                                 float* __restrict__ hid, int r0) {
    __shared__ unsigned short Ah[128 * 32], Al[128 * 32], Bh[128 * 32], Bl[128 * 32];
    const int tid = threadIdx.x;
    const int lane = tid & 63;
    const int wave = tid >> 6;
    const int bm = blockIdx.x * 128;            // chunk-local m tile
    const int bn = blockIdx.y * 128;            // n tile
    const int wm = (wave & 1) * 64;
    const int wn = (wave >> 1) * 64;
    const int lm = lane & 15;                   // row within 16
    const int kq = (lane >> 4) * 8;             // k octet

    f32x4 acc[4][4];
#pragma unroll
    for (int i = 0; i < 4; ++i)
#pragma unroll
        for (int j = 0; j < 4; ++j) acc[i][j] = (f32x4){0.f, 0.f, 0.f, 0.f};

    for (int k0 = 0; k0 < Kdim; k0 += 32) {
        __syncthreads();
#pragma unroll
        for (int t = 0; t < 2; ++t) {
            const int c = tid + t * 256;        // 0..511
            const int row = c >> 2;             // 0..127
            const int ko = (c & 3) * 8;         // 0,8,16,24
            const size_t ga = (size_t)(r0 + bm + row) * Kdim + k0 + ko;
            const size_t gb = (size_t)(bn + row) * Kdim + k0 + ko;
            *(uint4*)&Ah[row * 32 + ko] = *(const uint4*)(Ahi + ga);
            *(uint4*)&Al[row * 32 + ko] = *(const uint4*)(Alo + ga);
            *(uint4*)&Bh[row * 32 + ko] = *(const uint4*)(Bhi + gb);
            *(uint4*)&Bl[row * 32 + ko] = *(const uint4*)(Blo + gb);
        }
        __syncthreads();

        bf16x8 ah[4], al[4], bh[4], bl[4];
#pragma unroll
        for (int i = 0; i < 4; ++i) {
            ah[i] = *(const bf16x8*)&Ah[(wm + i * 16 + lm) * 32 + kq];
            al[i] = *(const bf16x8*)&Al[(wm + i * 16 + lm) * 32 + kq];
            bh[i] = *(const bf16x8*)&Bh[(wn + i * 16 + lm) * 32 + kq];
            bl[i] = *(const bf16x8*)&Bl[(wn + i * 16 + lm) * 32 + kq];
        }
#pragma unroll
        for (int i = 0; i < 4; ++i)
#pragma unroll
            for (int j = 0; j < 4; ++j) {
                acc[i][j] = __builtin_amdgcn_mfma_f32_16x16x32_bf16(ah[i], bh[j], acc[i][j], 0, 0, 0);
                acc[i][j] = __builtin_amdgcn_mfma_f32_16x16x32_bf16(ah[i], bl[j], acc[i][j], 0, 0, 0);
                acc[i][j] = __builtin_amdgcn_mfma_f32_16x16x32_bf16(al[i], bh[j], acc[i][j], 0, 0, 0);
            }
    }

    // epilogue: C/D layout col=lane&15, row=(lane>>4)*4+reg  [m89/m91 verified]
    const int rbase = (lane >> 4) * 4;
#pragma unroll
    for (int j = 0; j < 4; ++j) {
        const int n = bn + wn + j * 16 + lm;
        const float bj = bias[n];
#pragma unroll
        for (int i = 0; i < 4; ++i) {
            const int m0 = bm + wm + i * 16 + rbase;
#pragma unroll
            for (int r2 = 0; r2 < 4; ++r2)
                hid[(size_t)(m0 + r2) * Ncols + n] = acc[i][j][r2] + bj;
        }
    }
}

// ---------------- Phase 2: softmax x2, argmax, codevectors, marginal ----------
__global__ __launch_bounds__(256) void phase2(const float* __restrict__ hid,
                                              const float* __restrict__ u,
                                              const float* __restrict__ emb,
                                              const int* __restrict__ mask,
                                              float* __restrict__ marginal,
                                              float* __restrict__ out,
                                              int r0) {
    const int g = blockIdx.y;
    const int n0 = r0 + blockIdx.x * 8;
    const int tid = threadIdx.x;
    const int lane = tid & 63;
    const int wid = tid >> 6;

    __shared__ float marg_s[32 * 256];   // private column per thread
    __shared__ float sv1[4]; __shared__ int si1[4]; __shared__ float sv2[4];
    __shared__ float ss1[4], ss2[4], scv[4][8];

#pragma unroll
    for (int i = 0; i < 32; ++i) marg_s[(i << 8) + tid] = 0.f;

    const float* embg = emb + (size_t)g * Vsz * 8;
    float lg[32];

    for (int r = 0; r < 8; ++r) {
        const int n = n0 + r;
        const float* hrow = hid + (size_t)(n - r0) * Ncols + (size_t)g * Vsz;
        const float* urow = u + ((size_t)n * 2 + g) * Vsz;

        // pass A: noisy logits, running maxes
        float mx1 = -INFINITY, mx2 = -INFINITY;
        int amax = 0;
#pragma unroll
        for (int i = 0; i < 32; ++i) {
            const int v = (i << 8) + tid;
            const float hv = hrow[v];
            float uu = urow[v];
            uu = fminf(fmaxf(uu, 1.17549435e-38f), 1.0f);
            const float d = uu - 1.0f;
            // -log(u) via log1p Taylor for u>0.8 (hw log abs-error zone), else native
            float q = 1.0f / 9.0f;
            q = fmaf(q, d, -0.125f);
            q = fmaf(q, d, 1.0f / 7.0f);
            q = fmaf(q, d, -1.0f / 6.0f);
            q = fmaf(q, d, 0.2f);
            q = fmaf(q, d, -0.25f);
            q = fmaf(q, d, 1.0f / 3.0f);
            q = fmaf(q, d, -0.5f);
            q = fmaf(q, d, 1.0f);
            const float inner = (d > -0.2f) ? (-d) * q : -__logf(uu);
            const float l = hv - __logf(inner);   // h + gumbel
            lg[i] = l;
            if (l > mx1) { mx1 = l; amax = v; }
            mx2 = fmaxf(mx2, hv);
        }
        float v1 = mx1; int i1 = amax; float v2 = mx2;
#pragma unroll
        for (int off = 32; off > 0; off >>= 1) {
            const float ov = __shfl_down(v1, off);
            const int oi = __shfl_down(i1, off);
            if (ov > v1 || (ov == v1 && oi < i1)) { v1 = ov; i1 = oi; }
            v2 = fmaxf(v2, __shfl_down(v2, off));
        }
        if (lane == 0) { sv1[wid] = v1; si1[wid] = i1; sv2[wid] = v2; }
        __syncthreads();
        if (tid == 0) {
            float bv = sv1[0]; int bi = si1[0]; float b2 = sv2[0];
            for (int w2 = 1; w2 < 4; ++w2) {
                if (sv1[w2] > bv || (sv1[w2] == bv && si1[w2] < bi)) { bv = sv1[w2]; bi = si1[w2]; }
                b2 = fmaxf(b2, sv2[w2]);
            }
            sv1[0] = bv; si1[0] = bi; sv2[0] = b2;
        }
        __syncthreads();
        const float M1 = sv1[0];
        const float M2 = sv2[0];
        const int AMAX = si1[0];

        // pass B: sums + codevectors; lg[] becomes clean exp terms
        float s1 = 0.f, s2 = 0.f;
        float cv[8];
#pragma unroll
        for (int d2 = 0; d2 < 8; ++d2) cv[d2] = 0.f;
#pragma unroll
        for (int i = 0; i < 32; ++i) {
            const int v = (i << 8) + tid;
            const float p = __expf(lg[i] - M1);
            s1 += p;
            const float4 e0 = *(const float4*)(embg + (size_t)v * 8);
            const float4 e1 = *(const float4*)(embg + (size_t)v * 8 + 4);
            cv[0] = fmaf(p, e0.x, cv[0]); cv[1] = fmaf(p, e0.y, cv[1]);
            cv[2] = fmaf(p, e0.z, cv[2]); cv[3] = fmaf(p, e0.w, cv[3]);
            cv[4] = fmaf(p, e1.x, cv[4]); cv[5] = fmaf(p, e1.y, cv[5]);
            cv[6] = fmaf(p, e1.z, cv[6]); cv[7] = fmaf(p, e1.w, cv[7]);
            const float qq = __expf(hrow[v] - M2);   // hid re-read: L2 hit
            s2 += qq;
            lg[i] = qq;
        }
#pragma unroll
        for (int off = 32; off > 0; off >>= 1) {
            s1 += __shfl_down(s1, off);
            s2 += __shfl_down(s2, off);
        }
#pragma unroll
        for (int d2 = 0; d2 < 8; ++d2)
#pragma unroll
            for (int off = 32; off > 0; off >>= 1) cv[d2] += __shfl_down(cv[d2], off);
        if (lane == 0) {
            ss1[wid] = s1; ss2[wid] = s2;
#pragma unroll
            for (int d2 = 0; d2 < 8; ++d2) scv[wid][d2] = cv[d2];
        }
        __syncthreads();
        if (tid == 0) {
            ss1[0] = ss1[0] + ss1[1] + ss1[2] + ss1[3];
            ss2[0] = ss2[0] + ss2[1] + ss2[2] + ss2[3];
        }
        __syncthreads();
        const float S1 = ss1[0];
        const float S2 = ss2[0];
        if (tid < 8) {
            const float c = scv[0][tid] + scv[1][tid] + scv[2][tid] + scv[3][tid];
            out[(size_t)n * 16 + g * 8 + tid] = c / S1;
        }
        if (tid == 8) out[65537 + (size_t)n * 2 + g] = (float)AMAX;

        if (mask[n] != 0) {
            const float invS2 = 1.0f / S2;
#pragma unroll
            for (int i = 0; i < 32; ++i)
                marg_s[(i << 8) + tid] = fmaf(lg[i], invS2, marg_s[(i << 8) + tid]);
        }
        __syncthreads();   // shared arrays rewritten next row
    }
#pragma unroll
    for (int i = 0; i < 32; ++i)
        atomicAdd(&marginal[g * Vsz + (i << 8) + tid], marg_s[(i << 8) + tid]);
}

// ---------------- Perplexity --------------------------------------------------
__global__ __launch_bounds__(256) void ppl_kernel(const float* __restrict__ marginal,
                                                  const int* __restrict__ mask,
                                                  float* __restrict__ out) {
    const int tid = threadIdx.x;
    const int lane = tid & 63;
    const int wid = tid >> 6;
    __shared__ float red[4];
    __shared__ int redi[4];

    int ms = 0;
    for (int i = tid; i < Mrows; i += 256) ms += mask[i];
#pragma unroll
    for (int off = 32; off > 0; off >>= 1) ms += __shfl_down(ms, off);
    if (lane == 0) redi[wid] = ms;
    __syncthreads();
    const float inv = 1.0f / (float)(redi[0] + redi[1] + redi[2] + redi[3]);

    float ppl = 0.f;
    for (int g = 0; g < 2; ++g) {
        float part = 0.f;
        for (int v = tid; v < Vsz; v += 256) {
            const float m = marginal[g * Vsz + v] * inv;
            part += m * logf(m + 1e-7f);
        }
#pragma unroll
        for (int off = 32; off > 0; off >>= 1) part += __shfl_down(part, off);
        __syncthreads();
        if (lane == 0) red[wid] = part;
        __syncthreads();
        if (tid == 0) ppl += __expf(-(red[0] + red[1] + red[2] + red[3]));
        __syncthreads();
    }
    if (tid == 0) out[65536] = ppl;
}

// ---------------- Launch ------------------------------------------------------
extern "C" void kernel_launch(void* const* d_in, const int* in_sizes, int n_in,
                              void* d_out, int out_size, void* d_ws, size_t ws_size,
                              hipStream_t stream) {
    const float* x    = (const float*)d_in[0];
    const float* u    = (const float*)d_in[1];
    const float* emb  = (const float*)d_in[2];
    const float* w    = (const float*)d_in[3];
    const float* bias = (const float*)d_in[4];
    const int*   mask = (const int*)d_in[5];
    float* out = (float*)d_out;

    char* base = (char*)d_ws;
    float* marginal = (float*)base;                                    // 64 KB
    __hip_bfloat16* Ahi = (__hip_bfloat16*)(base + 65536);             // 2 MB
    __hip_bfloat16* Alo = Ahi + 1048576;                               // 2 MB
    __hip_bfloat16* Bhi = Alo + 1048576;                               // 8 MB
    __hip_bfloat16* Blo = Bhi + 4194304;                               // 8 MB
    const size_t hid_off = 65536 + 4194304 + 16777216;                 // 21037056
    float* hid = (float*)(base + hid_off);

    size_t cap_rows = (ws_size > hid_off) ? (ws_size - hid_off) / ((size_t)Ncols * 4) : 0;
    int cr = (cap_rows >= Mrows) ? Mrows : (int)((cap_rows / 128) * 128);
    if (cr < 128) cr = 128;

    hipMemsetAsync(marginal, 0, 65536, stream);
    split_bf16<<<4096, 256, 0, stream>>>(x, Ahi, Alo);      // 1M elems
    split_bf16<<<16384, 256, 0, stream>>>(w, Bhi, Blo);     // 4M elems

    for (int r0 = 0; r0 < Mrows; r0 += cr) {
        const int rows = (Mrows - r0 < cr) ? (Mrows - r0) : cr;
        dim3 gg(rows / 128, Ncols / 128);
        gemm_mfma<<<gg, 256, 0, stream>>>(Ahi, Alo, Bhi, Blo, bias, hid, r0);
        dim3 pg(rows / 8, 2);
        phase2<<<pg, 256, 0, stream>>>(hid, u, emb, mask, marginal, out, r0);
    }
    ppl_kernel<<<1, 256, 0, stream>>>(marginal, mask, out);
}